// Round 9
// baseline (1931.137 us; speedup 1.0000x reference)
//
#include <hip/hip_runtime.h>

// GRU decoder, bf16 MFMA. R16: de-synchronize the weight-fragment convoy.
// R15 post-mortem: GLL ring worked (FETCH 4.09->2.54GB, WRITE 152->98MB,
// zero staging regs) and duration DID NOT MOVE. Across R7-R15, dur is
// invariant (~1500-1650us) while traffic, registers, pipelining and
// occupancy all varied -> not BW/spill/TLP-bound. The invariant is the
// ACCESS PATTERN IN TIME: all 256 blocks run barrier-paced lockstep and
// at each kt request the SAME 3KB of fragments in the same microsecond --
// a 256-way same-cache-line burst (serialized L2 multicast + HBM burst
// queuing on the ~26% misses) at every kt of every step.
// Single change vs R15: per-block K-tile rotation kk=(kt+blockIdx%10)%10.
// Accumulation commutes -> identical math; instantaneous fragment demand
// spreads over all 480 frags instead of 48.

#define Bdim 8192
#define Tdim 96
#define Fdim 64
#define Hdim 256
#define BM   32
#define XS   72    // feat row stride (bf16): 64 + 8 pad
#define HS   264   // h row stride (bf16): 256 + 8 pad

typedef __attribute__((ext_vector_type(8))) short s16x8;
typedef __attribute__((ext_vector_type(4))) float f32x4;

#define MFMA __builtin_amdgcn_mfma_f32_16x16x32_bf16

// global(as1) -> LDS(as3) direct 16B/lane copy; dest is wave-uniform base,
// HW adds lane*16 (m104/m173: do NOT add a per-lane LDS offset).
#define GLL(gp, lp) __builtin_amdgcn_global_load_lds(                      \
    (const __attribute__((address_space(1))) void*)(gp),                   \
    (__attribute__((address_space(3))) void*)(lp), 16, 0, 0)

// s_waitcnt imm encoding (gfx9 lineage): [3:0]=vmcnt lo, [6:4]=expcnt,
// [11:8]=lgkmcnt, [15:14]=vmcnt hi.
#define WAIT_VMCNT3 do { __builtin_amdgcn_s_waitcnt(0x0F73);               \
                         __builtin_amdgcn_sched_barrier(0); } while (0)
#define WAIT_LGKM0  do { __builtin_amdgcn_s_waitcnt(0xC07F);               \
                         __builtin_amdgcn_sched_barrier(0); } while (0)

__device__ __forceinline__ unsigned short f2bf(float f) {
    union { float f; unsigned u; } v; v.f = f;
    unsigned r = v.u + 0x7FFFu + ((v.u >> 16) & 1u);   // RNE
    return (unsigned short)(r >> 16);
}

__device__ __forceinline__ float sigm_fast(float x) {
    return __builtin_amdgcn_rcpf(1.0f + __expf(-x));
}
__device__ __forceinline__ float tanh_fast(float x) {
    return 1.0f - 2.0f * __builtin_amdgcn_rcpf(1.0f + __expf(2.0f * x));
}

// ---- one-time weight conversion + B-fragment swizzle (unchanged) ----
// frag f = ((w*10 + kt)*3 + g)*2 + n2, lane l: 8 bf16 at sW[f*512 + l*8].
// lane holds B[k][n], k = kt*32 + (l>>4)*8 + j, n = g*256 + w*32 + n2*16 + (l&15).
// kt 0..7: B row k = Wr[k]; kt 8..9: B row = Wk[1 + (kt-8)*32 + (l>>4)*8 + j].
__global__ void prep_swz(const float* __restrict__ Wk, const float* __restrict__ Wr,
                         unsigned short* __restrict__ sW) {
    int idx = blockIdx.x * blockDim.x + threadIdx.x;
    if (idx >= 480 * 64) return;
    int lane = idx & 63, f = idx >> 6;
    int n2 = f & 1;
    int g  = (f >> 1) % 3;
    int kt = (f / 6) % 10;
    int w  = f / 60;
    int q = lane >> 4, cc = lane & 15;
    int n = g * 256 + w * 32 + n2 * 16 + cc;
    unsigned short* d = sW + (size_t)idx * 8;
#pragma unroll
    for (int j = 0; j < 8; ++j) {
        float v;
        if (kt < 8) v = Wr[(size_t)(kt * 32 + q * 8 + j) * 768 + n];
        else        v = Wk[(size_t)(1 + (kt - 8) * 32 + q * 8 + j) * 768 + n];
        d[j] = f2bf(v);
    }
}

__launch_bounds__(1024)
__global__ void gru_mfma16(
    const float* __restrict__ feat,       // [B,T,F]
    const float* __restrict__ init_state, // [B,H]
    const float* __restrict__ init_inp,   // [B,1]
    const unsigned short* __restrict__ sW,
    const float* __restrict__ Wk,         // row 0 (prev_out rank-1 term)
    const float* __restrict__ ib, const float* __restrict__ rb,
    const float* __restrict__ dw, const float* __restrict__ db,
    float* __restrict__ out)              // [B,T,1]
{
    __shared__ __align__(16) unsigned short xs[2][BM * XS];          // 9.2 KB
    __shared__ __align__(16) unsigned short hs[2][BM * HS];          // 33.8 KB
    __shared__ __align__(16) unsigned short wring[16 * 2 * 3 * 512]; // 96 KB
    __shared__ float wpart[2][16][BM];                               // 4 KB

    const int tid  = threadIdx.x;
    const int lane = tid & 63;
    const int wv   = tid >> 6;     // wave 0..15: 16 cols per gate
    const int q    = lane >> 4;
    const int c    = lane & 15;
    const int b0   = blockIdx.x * BM;
    const int col  = wv * 16 + c;  // column within each gate, 0..255
    const int koff = blockIdx.x % 10;   // per-block K-tile rotation

    // per-lane epilogue constants (n2 folded into wv)
    const float bz   = ib[col]       + rb[col];
    const float brr  = ib[256 + col] + rb[256 + col];
    const float bxh  = ib[512 + col];
    const float bhh  = rb[512 + col];
    const float wk0z = Wk[col];
    const float wk0r = Wk[256 + col];
    const float wk0h = Wk[512 + col];
    const float dwv  = dw[col];
    const float dbv  = db[0];

    // init h: fp32 in regs + bf16 in LDS (buffer 0)
    float hreg[2][4];     // [mt][i], single column per lane
#pragma unroll
    for (int mt = 0; mt < 2; ++mt)
#pragma unroll
        for (int i = 0; i < 4; ++i) {
            int row = mt * 16 + q * 4 + i;
            float v = init_state[(size_t)(b0 + row) * Hdim + col];
            hreg[mt][i] = v;
            hs[0][row * HS + col] = f2bf(v);
        }

    // seed wpart[1] so the t=0 finish-phase synthesizes prev_out=init_inp
    if (tid < 16 * BM) {
        int ww = tid >> 5, r = tid & 31;
        wpart[1][ww][r] = (ww == 0) ? (init_inp[b0 + r] - dbv) : 0.0f;
    }

    // stage feat t=0 (1024 threads: 32 rows x 32 float2)
    {
        int r = tid >> 5, fi = tid & 31;
        float2 f = *(const float2*)&feat[((size_t)(b0 + r) * Tdim + 0) * Fdim + fi * 2];
        ushort2 p; p.x = f2bf(f.x); p.y = f2bf(f.y);
        *(ushort2*)&xs[0][r * XS + fi * 2] = p;
    }

    // per-lane global frag base (lane*16B mirrors GLL's implicit dest stride)
    const unsigned short* wp0 =
        sW + ((size_t)(wv >> 1) * 60 + (wv & 1)) * 512 + lane * 8;
    // per-wave ring base (shorts); slot s frag g at + s*1536 + g*512
    const int rbase = wv * 3072;

    // prologue: stage rotated kt=0 -> slot0, kt=1 -> slot1
#pragma unroll
    for (int k0 = 0; k0 < 2; ++k0) {
        int kk = k0 + koff; if (kk >= 10) kk -= 10;
#pragma unroll
        for (int g = 0; g < 3; ++g)
            GLL(wp0 + (size_t)(kk * 3 + g) * 1024,
                &wring[rbase + k0 * 1536 + g * 512]);
    }

    __syncthreads();

    for (int t = 0; t < Tdim; ++t) {
        const unsigned short* hsp = hs[t & 1];
        const unsigned short* xsp = xs[t & 1];

        // feat t+1 issued FIRST: oldest in vmcnt queue (count-safety) and
        // gets the whole K-loop as latency cover. Written to xs post-S1.
        float2 fnext;
        int fr = tid >> 5, ffi = tid & 31;
        if (t + 1 < Tdim)
            fnext = *(const float2*)&feat[((size_t)(b0 + fr) * Tdim + (t + 1)) * Fdim + ffi * 2];

        f32x4 az[2], ar[2], ax[2], ah[2];   // [mt]
#pragma unroll
        for (int mt = 0; mt < 2; ++mt) {
            az[mt] = (f32x4)0.0f; ar[mt] = (f32x4)0.0f;
            ax[mt] = (f32x4)0.0f; ah[mt] = (f32x4)0.0f;
        }

        // ---- K-loop (rotated): b-frags from LDS ring, depth-2 gll ----
#pragma unroll
        for (int kt = 0; kt < 10; ++kt) {
            const int slot = kt & 1;
            int kk = kt + koff; if (kk >= 10) kk -= 10;   // rotated tile

            WAIT_VMCNT3;   // this kt's 3 frags have landed in LDS

            const unsigned short* bs = &wring[rbase + slot * 1536 + lane * 8];
            s16x8 w0 = *(const s16x8*)(bs + 0 * 512);
            s16x8 w1 = *(const s16x8*)(bs + 1 * 512);
            s16x8 w2 = *(const s16x8*)(bs + 2 * 512);
            s16x8 a0, a1;
            if (kk < 8) {
                a0 = *(const s16x8*)&hsp[c * HS + kk * 32 + q * 8];
                a1 = *(const s16x8*)&hsp[(16 + c) * HS + kk * 32 + q * 8];
            } else {
                a0 = *(const s16x8*)&xsp[c * XS + (kk - 8) * 32 + q * 8];
                a1 = *(const s16x8*)&xsp[(16 + c) * XS + (kk - 8) * 32 + q * 8];
            }

            WAIT_LGKM0;    // slot reads retired -> safe to overwrite
            {
                int kn = kk + 2; if (kn >= 10) kn -= 10;  // wraps into next step
#pragma unroll
                for (int g = 0; g < 3; ++g)
                    GLL(wp0 + (size_t)(kn * 3 + g) * 1024,
                        &wring[rbase + slot * 1536 + g * 512]);
            }

            az[0] = MFMA(a0, w0, az[0], 0, 0, 0);
            az[1] = MFMA(a1, w0, az[1], 0, 0, 0);
            ar[0] = MFMA(a0, w1, ar[0], 0, 0, 0);
            ar[1] = MFMA(a1, w1, ar[1], 0, 0, 0);
            if (kk < 8) {   // hh terms
                ah[0] = MFMA(a0, w2, ah[0], 0, 0, 0);
                ah[1] = MFMA(a1, w2, ah[1], 0, 0, 0);
            } else {        // xh terms
                ax[0] = MFMA(a0, w2, ax[0], 0, 0, 0);
                ax[1] = MFMA(a1, w2, ax[1], 0, 0, 0);
            }
        }

        __syncthreads();   // S1: hs/xs reads done; wpart(t-1) complete

        // ---- finish step t-1's dense output; prev_out in 's' ----
        float s;
        {
            int r = lane & 31;
            s = dbv;
            const float (*wp)[BM] = wpart[(t - 1) & 1];
#pragma unroll
            for (int ww = 0; ww < 16; ++ww) s += wp[ww][r];
            if (t > 0 && wv == 0 && lane < 32)
                out[(size_t)(b0 + r) * Tdim + (t - 1)] = s;
        }

        // ---- epilogue: gates, h update, fused dense partial reduce ----
        unsigned short* hsn = hs[(t + 1) & 1];
#pragma unroll
        for (int mt = 0; mt < 2; ++mt)
#pragma unroll
            for (int i = 0; i < 4; ++i) {
                float pv = __shfl(s, mt * 16 + q * 4 + i, 64);
                float zz = sigm_fast(az[mt][i] + bz + pv * wk0z);
                float rr = sigm_fast(ar[mt][i] + brr + pv * wk0r);
                float cd = tanh_fast(ax[mt][i] + bxh + pv * wk0h +
                                     rr * (ah[mt][i] + bhh));
                float hn = zz * hreg[mt][i] + (1.0f - zz) * cd;
                hreg[mt][i] = hn;
                hsn[(mt * 16 + q * 4 + i) * HS + col] = f2bf(hn);
                float sp = hn * dwv;
                sp += __shfl_xor(sp, 1, 64);
                sp += __shfl_xor(sp, 2, 64);
                sp += __shfl_xor(sp, 4, 64);
                sp += __shfl_xor(sp, 8, 64);
                if (c == 0) wpart[t & 1][wv][mt * 16 + q * 4 + i] = sp;
            }

        // late half of the feat stage
        if (t + 1 < Tdim) {
            ushort2 p; p.x = f2bf(fnext.x); p.y = f2bf(fnext.y);
            *(ushort2*)&xs[(t + 1) & 1][fr * XS + ffi * 2] = p;
        }
        __syncthreads();   // S2: hs/wpart/xs writes visible for next step
    }

    // final dense output for t=95
    {
        int r = lane & 31;
        float s = dbv;
        const float (*wp)[BM] = wpart[(Tdim - 1) & 1];
#pragma unroll
        for (int ww = 0; ww < 16; ++ww) s += wp[ww][r];
        if (wv == 0 && lane < 32)
            out[(size_t)(b0 + r) * Tdim + (Tdim - 1)] = s;
    }
}

extern "C" void kernel_launch(void* const* d_in, const int* in_sizes, int n_in,
                              void* d_out, int out_size, void* d_ws, size_t ws_size,
                              hipStream_t stream) {
    const float* feat       = (const float*)d_in[0];
    const float* init_state = (const float*)d_in[1];
    const float* init_inp   = (const float*)d_in[2];
    const float* Wk         = (const float*)d_in[3];
    const float* Wr         = (const float*)d_in[4];
    const float* ib         = (const float*)d_in[5];
    const float* rb         = (const float*)d_in[6];
    const float* dw         = (const float*)d_in[7];
    const float* db         = (const float*)d_in[8];
    float* out              = (float*)d_out;

    unsigned short* sW = (unsigned short*)d_ws;   // 480 frags * 1 KB = 480 KB

    prep_swz<<<120, 256, 0, stream>>>(Wk, Wr, sW);
    gru_mfma16<<<Bdim / BM, 1024, 0, stream>>>(
        feat, init_state, init_inp, sW, Wk, ib, rb, dw, db, out);
}

// Round 10
// 1535.664 us; speedup vs baseline: 1.2575x; 1.2575x over previous
//
#include <hip/hip_runtime.h>

// GRU decoder, bf16 MFMA. R17: kill the last spills (register diet) +
// let the weight pipeline survive barriers (raw s_barrier + counted waits).
// R16 post-mortem: rotation REGRESSED (1824, FETCH up 27%) -- lockstep
// convoy is good for L2 multicast; reverted. 9-round record: dur pinned
// ~1500-1650 while FETCH varied 1.7x and every weight-path variant tied.
// Two invariants remain: (1) ~500B/thread scratch in EVERY round (VGPR
// pinned at the 64-arch cap; live scratch ~13MB/XCD thrashes L2 ->
// 2.5-4.3GB fill from 210MB compulsory); (2) __syncthreads drains
// vmcnt(0) twice per step -> weight pipeline restarts cold every step.
// Changes vs R15 (best-FETCH variant):
//  * epilogue per-col constants (8 floats) -> 8KB LDS table, loaded only
//    inside the epilogue; dbv -> SGPR via readfirstlane. K-loop arch-reg
//    peak ~48 < 64 -> no forced spills.
//  * in-loop barriers are raw s_barrier: S1 needs no waits (ds_reads
//    drained per-kt), S2 needs lgkmcnt(0) only. Ring GLLs + fnext stay
//    in flight across barriers; vmcnt(3) traced conservative-correct
//    across the step boundary.
//  * koff rotation reverted (R16).

#define Bdim 8192
#define Tdim 96
#define Fdim 64
#define Hdim 256
#define BM   32
#define XS   72    // feat row stride (bf16): 64 + 8 pad
#define HS   264   // h row stride (bf16): 256 + 8 pad

typedef __attribute__((ext_vector_type(8))) short s16x8;
typedef __attribute__((ext_vector_type(4))) float f32x4;

#define MFMA __builtin_amdgcn_mfma_f32_16x16x32_bf16

// global(as1) -> LDS(as3) direct 16B/lane copy; dest is wave-uniform base,
// HW adds lane*16.
#define GLL(gp, lp) __builtin_amdgcn_global_load_lds(                      \
    (const __attribute__((address_space(1))) void*)(gp),                   \
    (__attribute__((address_space(3))) void*)(lp), 16, 0, 0)

// s_waitcnt imm encoding (gfx9 lineage): [3:0]=vmcnt lo, [6:4]=expcnt,
// [11:8]=lgkmcnt, [15:14]=vmcnt hi.
#define WAIT_VMCNT3 do { __builtin_amdgcn_s_waitcnt(0x0F73);               \
                         __builtin_amdgcn_sched_barrier(0); } while (0)
#define WAIT_LGKM0  do { __builtin_amdgcn_s_waitcnt(0xC07F);               \
                         __builtin_amdgcn_sched_barrier(0); } while (0)
#define RAW_BAR     do { __builtin_amdgcn_sched_barrier(0);                \
                         __builtin_amdgcn_s_barrier();                     \
                         __builtin_amdgcn_sched_barrier(0); } while (0)

__device__ __forceinline__ unsigned short f2bf(float f) {
    union { float f; unsigned u; } v; v.f = f;
    unsigned r = v.u + 0x7FFFu + ((v.u >> 16) & 1u);   // RNE
    return (unsigned short)(r >> 16);
}

__device__ __forceinline__ float sigm_fast(float x) {
    return __builtin_amdgcn_rcpf(1.0f + __expf(-x));
}
__device__ __forceinline__ float tanh_fast(float x) {
    return 1.0f - 2.0f * __builtin_amdgcn_rcpf(1.0f + __expf(2.0f * x));
}

// ---- one-time weight conversion + B-fragment swizzle (unchanged) ----
__global__ void prep_swz(const float* __restrict__ Wk, const float* __restrict__ Wr,
                         unsigned short* __restrict__ sW) {
    int idx = blockIdx.x * blockDim.x + threadIdx.x;
    if (idx >= 480 * 64) return;
    int lane = idx & 63, f = idx >> 6;
    int n2 = f & 1;
    int g  = (f >> 1) % 3;
    int kt = (f / 6) % 10;
    int w  = f / 60;
    int q = lane >> 4, cc = lane & 15;
    int n = g * 256 + w * 32 + n2 * 16 + cc;
    unsigned short* d = sW + (size_t)idx * 8;
#pragma unroll
    for (int j = 0; j < 8; ++j) {
        float v;
        if (kt < 8) v = Wr[(size_t)(kt * 32 + q * 8 + j) * 768 + n];
        else        v = Wk[(size_t)(1 + (kt - 8) * 32 + q * 8 + j) * 768 + n];
        d[j] = f2bf(v);
    }
}

__launch_bounds__(1024)
__global__ void gru_mfma17(
    const float* __restrict__ feat,       // [B,T,F]
    const float* __restrict__ init_state, // [B,H]
    const float* __restrict__ init_inp,   // [B,1]
    const unsigned short* __restrict__ sW,
    const float* __restrict__ Wk,         // row 0 (prev_out rank-1 term)
    const float* __restrict__ ib, const float* __restrict__ rb,
    const float* __restrict__ dw, const float* __restrict__ db,
    float* __restrict__ out)              // [B,T,1]
{
    __shared__ __align__(16) unsigned short xs[2][BM * XS];          // 9.2 KB
    __shared__ __align__(16) unsigned short hs[2][BM * HS];          // 33.8 KB
    __shared__ __align__(16) unsigned short wring[16 * 2 * 3 * 512]; // 96 KB
    __shared__ float wpart[2][16][BM];                               // 4 KB
    __shared__ float cst[8][256];                                    // 8 KB

    const int tid  = threadIdx.x;
    const int lane = tid & 63;
    const int wv   = tid >> 6;     // wave 0..15: 16 cols per gate
    const int q    = lane >> 4;
    const int c    = lane & 15;
    const int b0   = blockIdx.x * BM;
    const int col  = wv * 16 + c;  // column within each gate, 0..255

    // dbv in SGPR (wave-uniform)
    float dbv;
    {
        union { float f; int i; } u; u.f = db[0];
        u.i = __builtin_amdgcn_readfirstlane(u.i);
        dbv = u.f;
    }

    // per-col epilogue constants -> LDS table (dead during K-loop)
    {
        int cc2 = tid & 255;
        int j0  = tid >> 8;        // 0..3
#pragma unroll
        for (int jj2 = 0; jj2 < 2; ++jj2) {
            int jj = j0 + jj2 * 4; // 0..7
            float v;
            switch (jj) {
                case 0: v = ib[cc2]       + rb[cc2];       break;
                case 1: v = ib[256 + cc2] + rb[256 + cc2]; break;
                case 2: v = ib[512 + cc2];                 break;
                case 3: v = rb[512 + cc2];                 break;
                case 4: v = Wk[cc2];                       break;
                case 5: v = Wk[256 + cc2];                 break;
                case 6: v = Wk[512 + cc2];                 break;
                default: v = dw[cc2];                      break;
            }
            cst[jj][cc2] = v;
        }
    }

    // init h: fp32 in regs + bf16 in LDS (buffer 0)
    float hreg[2][4];     // [mt][i], single column per lane
#pragma unroll
    for (int mt = 0; mt < 2; ++mt)
#pragma unroll
        for (int i = 0; i < 4; ++i) {
            int row = mt * 16 + q * 4 + i;
            float v = init_state[(size_t)(b0 + row) * Hdim + col];
            hreg[mt][i] = v;
            hs[0][row * HS + col] = f2bf(v);
        }

    // seed wpart[1] so the t=0 finish-phase synthesizes prev_out=init_inp
    if (tid < 16 * BM) {
        int ww = tid >> 5, r = tid & 31;
        wpart[1][ww][r] = (ww == 0) ? (init_inp[b0 + r] - dbv) : 0.0f;
    }

    // stage feat t=0 (1024 threads: 32 rows x 32 float2)
    {
        int r = tid >> 5, fi = tid & 31;
        float2 f = *(const float2*)&feat[((size_t)(b0 + r) * Tdim + 0) * Fdim + fi * 2];
        ushort2 p; p.x = f2bf(f.x); p.y = f2bf(f.y);
        *(ushort2*)&xs[0][r * XS + fi * 2] = p;
    }

    // per-lane global frag base (lane*16B mirrors GLL's implicit dest stride)
    const unsigned short* wp0 =
        sW + ((size_t)(wv >> 1) * 60 + (wv & 1)) * 512 + lane * 8;
    // per-wave ring base (shorts); slot s frag g at + s*1536 + g*512
    const int rbase = wv * 3072;

    // prologue: stage kt=0 -> slot0, kt=1 -> slot1 (drained by full barrier)
#pragma unroll
    for (int k0 = 0; k0 < 2; ++k0)
#pragma unroll
        for (int g = 0; g < 3; ++g)
            GLL(wp0 + (size_t)(k0 * 3 + g) * 1024,
                &wring[rbase + k0 * 1536 + g * 512]);

    __syncthreads();   // full drain, once

    for (int t = 0; t < Tdim; ++t) {
        const unsigned short* hsp = hs[t & 1];
        const unsigned short* xsp = xs[t & 1];

        // feat t+1 issued FIRST: oldest in vmcnt queue (count-safety).
        float2 fnext;
        int fr = tid >> 5, ffi = tid & 31;
        if (t + 1 < Tdim)
            fnext = *(const float2*)&feat[((size_t)(b0 + fr) * Tdim + (t + 1)) * Fdim + ffi * 2];

        f32x4 az[2], ar[2], ax[2], ah[2];   // [mt]
#pragma unroll
        for (int mt = 0; mt < 2; ++mt) {
            az[mt] = (f32x4)0.0f; ar[mt] = (f32x4)0.0f;
            ax[mt] = (f32x4)0.0f; ah[mt] = (f32x4)0.0f;
        }

        // ---- K-loop: b-frags from LDS ring, depth-2 gll pipeline ----
#pragma unroll
        for (int kt = 0; kt < 10; ++kt) {
            const int slot = kt & 1;
            WAIT_VMCNT3;   // this kt's 3 frags have landed in LDS

            const unsigned short* bs = &wring[rbase + slot * 1536 + lane * 8];
            s16x8 w0 = *(const s16x8*)(bs + 0 * 512);
            s16x8 w1 = *(const s16x8*)(bs + 1 * 512);
            s16x8 w2 = *(const s16x8*)(bs + 2 * 512);
            s16x8 a0, a1;
            if (kt < 8) {
                a0 = *(const s16x8*)&hsp[c * HS + kt * 32 + q * 8];
                a1 = *(const s16x8*)&hsp[(16 + c) * HS + kt * 32 + q * 8];
            } else {
                a0 = *(const s16x8*)&xsp[c * XS + (kt - 8) * 32 + q * 8];
                a1 = *(const s16x8*)&xsp[(16 + c) * XS + (kt - 8) * 32 + q * 8];
            }

            WAIT_LGKM0;    // slot reads retired -> safe to overwrite
            {
                const int ktn = (kt + 2) % 10;   // wraps into next step's kt0/1
#pragma unroll
                for (int g = 0; g < 3; ++g)
                    GLL(wp0 + (size_t)(ktn * 3 + g) * 1024,
                        &wring[rbase + slot * 1536 + g * 512]);
            }

            az[0] = MFMA(a0, w0, az[0], 0, 0, 0);
            az[1] = MFMA(a1, w0, az[1], 0, 0, 0);
            ar[0] = MFMA(a0, w1, ar[0], 0, 0, 0);
            ar[1] = MFMA(a1, w1, ar[1], 0, 0, 0);
            if (kt < 8) {   // hh terms
                ah[0] = MFMA(a0, w2, ah[0], 0, 0, 0);
                ah[1] = MFMA(a1, w2, ah[1], 0, 0, 0);
            } else {        // xh terms
                ax[0] = MFMA(a0, w2, ax[0], 0, 0, 0);
                ax[1] = MFMA(a1, w2, ax[1], 0, 0, 0);
            }
        }

        // S1: all this wave's ds_reads drained per-kt; no vmcnt drain ->
        // ring GLLs + fnext stay in flight across the barrier.
        RAW_BAR;

        // ---- finish step t-1's dense output; prev_out in 's' ----
        float s;
        {
            int r = lane & 31;
            s = dbv;
            const float (*wp)[BM] = wpart[(t - 1) & 1];
#pragma unroll
            for (int ww = 0; ww < 16; ++ww) s += wp[ww][r];
            if (t > 0 && wv == 0 && lane < 32)
                out[(size_t)(b0 + r) * Tdim + (t - 1)] = s;
        }

        // epilogue constants from LDS (registers only live here)
        const float bz   = cst[0][col];
        const float brr  = cst[1][col];
        const float bxh  = cst[2][col];
        const float bhh  = cst[3][col];
        const float wk0z = cst[4][col];
        const float wk0r = cst[5][col];
        const float wk0h = cst[6][col];
        const float dwv  = cst[7][col];

        // ---- epilogue: gates, h update, fused dense partial reduce ----
        unsigned short* hsn = hs[(t + 1) & 1];
#pragma unroll
        for (int mt = 0; mt < 2; ++mt)
#pragma unroll
            for (int i = 0; i < 4; ++i) {
                float pv = __shfl(s, mt * 16 + q * 4 + i, 64);
                float zz = sigm_fast(az[mt][i] + bz + pv * wk0z);
                float rr = sigm_fast(ar[mt][i] + brr + pv * wk0r);
                float cd = tanh_fast(ax[mt][i] + bxh + pv * wk0h +
                                     rr * (ah[mt][i] + bhh));
                float hn = zz * hreg[mt][i] + (1.0f - zz) * cd;
                hreg[mt][i] = hn;
                hsn[(mt * 16 + q * 4 + i) * HS + col] = f2bf(hn);
                float sp = hn * dwv;
                sp += __shfl_xor(sp, 1, 64);
                sp += __shfl_xor(sp, 2, 64);
                sp += __shfl_xor(sp, 4, 64);
                sp += __shfl_xor(sp, 8, 64);
                if (c == 0) wpart[t & 1][wv][mt * 16 + q * 4 + i] = sp;
            }

        // late half of the feat stage
        if (t + 1 < Tdim) {
            ushort2 p; p.x = f2bf(fnext.x); p.y = f2bf(fnext.y);
            *(ushort2*)&xs[(t + 1) & 1][fr * XS + ffi * 2] = p;
        }

        // S2: LDS writes must be visible -> lgkm drain only; GLLs fly on.
        WAIT_LGKM0;
        RAW_BAR;
    }

    // final dense output for t=95
    {
        int r = lane & 31;
        float s = dbv;
        const float (*wp)[BM] = wpart[(Tdim - 1) & 1];
#pragma unroll
        for (int ww = 0; ww < 16; ++ww) s += wp[ww][r];
        if (wv == 0 && lane < 32)
            out[(size_t)(b0 + r) * Tdim + (Tdim - 1)] = s;
    }
}

extern "C" void kernel_launch(void* const* d_in, const int* in_sizes, int n_in,
                              void* d_out, int out_size, void* d_ws, size_t ws_size,
                              hipStream_t stream) {
    const float* feat       = (const float*)d_in[0];
    const float* init_state = (const float*)d_in[1];
    const float* init_inp   = (const float*)d_in[2];
    const float* Wk         = (const float*)d_in[3];
    const float* Wr         = (const float*)d_in[4];
    const float* ib         = (const float*)d_in[5];
    const float* rb         = (const float*)d_in[6];
    const float* dw         = (const float*)d_in[7];
    const float* db         = (const float*)d_in[8];
    float* out              = (float*)d_out;

    unsigned short* sW = (unsigned short*)d_ws;   // 480 frags * 1 KB = 480 KB

    prep_swz<<<120, 256, 0, stream>>>(Wk, Wr, sW);
    gru_mfma17<<<Bdim / BM, 1024, 0, stream>>>(
        feat, init_state, init_inp, sW, Wk, ib, rb, dw, db, out);
}